// Round 1
// baseline (121.271 us; speedup 1.0000x reference)
//
#include <hip/hip_runtime.h>

#define N 512
#define KAPPA2 0.1089f   // 0.33^2
#define GAMMA  1.0f
#define BETA   25.0f

// state: [B=8, 9, 512, 512] f32. slices 0..6 = x_t, 7 = vx, 8 = vy.
// q[b] = |A x0|^2 + 1.05|x0|^2 + sum_{t=1..6}|Mx_t|^2 + sum_{t=1..5}|x_t|^2
//        - 2 * sum_{t=0..5} <x_t, Mx_{t+1}>
__global__ __launch_bounds__(256) void phi_q_kernel(const float* __restrict__ state,
                                                    float* __restrict__ out) {
    const int bid = blockIdx.x;          // 8 * 512 * 2 = 8192 blocks
    const int seg = bid & 1;             // x half-row segment
    const int y   = (bid >> 1) & (N - 1);
    const int b   = bid >> 10;
    const int x   = seg * 256 + threadIdx.x;

    const size_t slice = (size_t)N * N;
    const float* base = state + (size_t)b * 9 * slice;
    const size_t idx  = (size_t)y * N + x;

    const float vx = base[7 * slice + idx];
    const float vy = base[8 * slice + idx];
    const float H11 = GAMMA + BETA * vx * vx;
    const float H12 = BETA * vx * vy;
    const float H22 = GAMMA + BETA * vy * vy;

    const bool xm = (x > 0), xp = (x < N - 1);
    const bool ym = (y > 0), yp = (y < N - 1);

    float q = 0.0f;
    float prev_x = 0.0f;

    #pragma unroll
    for (int t = 0; t < 7; ++t) {
        const float* u = base + (size_t)t * slice;
        const float c  = u[idx];
        const float l  = xm ? u[idx - 1]     : 0.0f;
        const float r  = xp ? u[idx + 1]     : 0.0f;
        const float d  = ym ? u[idx - N]     : 0.0f;   // y-1
        const float g  = yp ? u[idx + N]     : 0.0f;   // y+1
        const float dl = (ym && xm) ? u[idx - N - 1] : 0.0f;
        const float dr = (ym && xp) ? u[idx - N + 1] : 0.0f;
        const float ul = (yp && xm) ? u[idx + N - 1] : 0.0f;
        const float ur = (yp && xp) ? u[idx + N + 1] : 0.0f;

        const float uxx = l + r - 2.0f * c;
        const float uyy = d + g - 2.0f * c;
        const float uxy = 0.25f * (ur - ul - dr + dl);

        const float div = H11 * uxx + 2.0f * H12 * uxy + H22 * uyy;
        const float Ax  = KAPPA2 * c - div;
        const float Mx  = c + Ax;   // DT = 1

        if (t == 0) {
            q += Ax * Ax + 1.05f * c * c;
        } else {
            q += Mx * Mx;
            if (t < 6) q += c * c;          // nx for t = 1..5
            q -= 2.0f * prev_x * Mx;        // cross: x_{t-1} * Mx_t
        }
        prev_x = c;
    }

    // --- block reduction ---
    #pragma unroll
    for (int off = 32; off > 0; off >>= 1)
        q += __shfl_down(q, off, 64);

    __shared__ float ws[4];
    const int lane = threadIdx.x & 63;
    const int wid  = threadIdx.x >> 6;
    if (lane == 0) ws[wid] = q;
    __syncthreads();
    if (threadIdx.x == 0) {
        atomicAdd(&out[b], ws[0] + ws[1] + ws[2] + ws[3]);
    }
}

extern "C" void kernel_launch(void* const* d_in, const int* in_sizes, int n_in,
                              void* d_out, int out_size, void* d_ws, size_t ws_size,
                              hipStream_t stream) {
    const float* state = (const float*)d_in[0];
    float* out = (float*)d_out;

    hipMemsetAsync(out, 0, (size_t)out_size * sizeof(float), stream);

    const int blocks = 8 * N * 2;   // batch * rows * 2 half-row segments
    phi_q_kernel<<<blocks, 256, 0, stream>>>(state, out);
}

// Round 3
// 33.279 us; speedup vs baseline: 3.6440x; 3.6440x over previous
//
#include <hip/hip_runtime.h>

#define N 512
#define KAPPA2 0.1089f   // 0.33^2
#define GAMMA  1.0f
#define BETA   25.0f

// Load 6-wide span u[x0-1 .. x0+4] (zero outside grid in x).
__device__ __forceinline__ void load6(const float* __restrict__ p,
                                      bool xm, bool xp, float r[6]) {
    const float4 v = *reinterpret_cast<const float4*>(p);
    r[0] = xm ? p[-1] : 0.0f;
    r[1] = v.x; r[2] = v.y; r[3] = v.z; r[4] = v.w;
    r[5] = xp ? p[4] : 0.0f;
}

__device__ __forceinline__ void zero6(float r[6]) {
    r[0] = 0.0f; r[1] = 0.0f; r[2] = 0.0f;
    r[3] = 0.0f; r[4] = 0.0f; r[5] = 0.0f;
}

// state: [B=8, 9, 512, 512] f32. slices 0..6 = x_t, 7 = vx, 8 = vy.
// Stage 1: each block computes a partial q over 2 rows, writes ws[blockIdx.x].
__global__ __launch_bounds__(256) void phi_q_stage1(const float* __restrict__ state,
                                                    float* __restrict__ ws) {
    const int bid = blockIdx.x;              // 8 * 256 = 2048 blocks
    const int b   = bid >> 8;
    const int rp  = bid & 255;               // row pair
    const int tid = threadIdx.x;
    const int y   = rp * 2 + (tid >> 7);     // 128 threads per row
    const int x0  = (tid & 127) << 2;        // 4 px per thread

    const size_t slice = (size_t)N * N;
    const float* base  = state + (size_t)b * 9 * slice;
    const size_t idx   = (size_t)y * N + x0;

    const bool xm = (x0 > 0), xp = (x0 < N - 4);
    const bool ym = (y > 0),  yp = (y < N - 1);

    const float4 vx4 = *reinterpret_cast<const float4*>(base + 7 * slice + idx);
    const float4 vy4 = *reinterpret_cast<const float4*>(base + 8 * slice + idx);
    float H11[4], H12[4], H22[4];
    {
        const float vxs[4] = {vx4.x, vx4.y, vx4.z, vx4.w};
        const float vys[4] = {vy4.x, vy4.y, vy4.z, vy4.w};
        #pragma unroll
        for (int j = 0; j < 4; ++j) {
            H11[j] = GAMMA + BETA * vxs[j] * vxs[j];
            H12[j] = BETA * vxs[j] * vys[j];
            H22[j] = GAMMA + BETA * vys[j] * vys[j];
        }
    }

    float q = 0.0f;
    float prevc[4] = {0.0f, 0.0f, 0.0f, 0.0f};

    #pragma unroll
    for (int t = 0; t < 7; ++t) {
        const float* u = base + (size_t)t * slice;
        float rm[6], rc[6], ru[6];

        load6(u + idx, xm, xp, rc);
        if (ym) load6(u + idx - N, xm, xp, rm);
        else    zero6(rm);
        if (yp) load6(u + idx + N, xm, xp, ru);
        else    zero6(ru);

        #pragma unroll
        for (int j = 0; j < 4; ++j) {
            const float c   = rc[j + 1];
            const float uxx = rc[j] + rc[j + 2] - 2.0f * c;
            const float uyy = rm[j + 1] + ru[j + 1] - 2.0f * c;
            const float uxy = 0.25f * (ru[j + 2] - ru[j] - rm[j + 2] + rm[j]);
            const float div = H11[j] * uxx + 2.0f * H12[j] * uxy + H22[j] * uyy;
            const float Ax  = KAPPA2 * c - div;
            const float Mx  = c + Ax;   // DT = 1

            if (t == 0) {
                q += Ax * Ax + 1.05f * c * c;
            } else {
                q += Mx * Mx;
                if (t < 6) q += c * c;
                q -= 2.0f * prevc[j] * Mx;
            }
            prevc[j] = c;
        }
    }

    // block reduction -> one partial per block
    #pragma unroll
    for (int off = 32; off > 0; off >>= 1)
        q += __shfl_down(q, off, 64);

    __shared__ float sred[4];
    const int lane = tid & 63;
    const int wid  = tid >> 6;
    if (lane == 0) sred[wid] = q;
    __syncthreads();
    if (tid == 0) ws[bid] = sred[0] + sred[1] + sred[2] + sred[3];
}

// Stage 2: 8 blocks, each reduces its 256 partials, direct store (no atomics).
__global__ __launch_bounds__(256) void phi_q_stage2(const float* __restrict__ ws,
                                                    float* __restrict__ out) {
    const int b = blockIdx.x;
    float v = ws[b * 256 + threadIdx.x];
    #pragma unroll
    for (int off = 32; off > 0; off >>= 1)
        v += __shfl_down(v, off, 64);

    __shared__ float sred[4];
    const int lane = threadIdx.x & 63;
    const int wid  = threadIdx.x >> 6;
    if (lane == 0) sred[wid] = v;
    __syncthreads();
    if (threadIdx.x == 0) out[b] = sred[0] + sred[1] + sred[2] + sred[3];
}

extern "C" void kernel_launch(void* const* d_in, const int* in_sizes, int n_in,
                              void* d_out, int out_size, void* d_ws, size_t ws_size,
                              hipStream_t stream) {
    const float* state = (const float*)d_in[0];
    float* out = (float*)d_out;
    float* ws  = (float*)d_ws;

    phi_q_stage1<<<2048, 256, 0, stream>>>(state, ws);
    phi_q_stage2<<<8, 256, 0, stream>>>(ws, out);
}

// Round 4
// 26.195 us; speedup vs baseline: 4.6296x; 1.2705x over previous
//
#include <hip/hip_runtime.h>

#define N 512
#define KAPPA2 0.1089f   // 0.33^2
#define GAMMA  1.0f
#define BETA   25.0f

// Load a 10-wide span s[0..9] covering px [x0-1 .. x0+8] for this lane's 8 px.
// Wave = full row: lane L owns px [8L, 8L+8). Edges come from neighbor lanes via
// shuffle; lane 0 / lane 63 get the Dirichlet zero boundary.
__device__ __forceinline__ void loadspan10(const float* __restrict__ p, int lane,
                                           float s[10]) {
    const float4 A = *reinterpret_cast<const float4*>(p);
    const float4 B = *reinterpret_cast<const float4*>(p + 4);
    s[1] = A.x; s[2] = A.y; s[3] = A.z; s[4] = A.w;
    s[5] = B.x; s[6] = B.y; s[7] = B.z; s[8] = B.w;
    const float lw = __shfl_up(B.w, 1, 64);
    const float rx = __shfl_down(A.x, 1, 64);
    s[0] = (lane == 0)  ? 0.0f : lw;
    s[9] = (lane == 63) ? 0.0f : rx;
}

__device__ __forceinline__ void zero10(float s[10]) {
    #pragma unroll
    for (int j = 0; j < 10; ++j) s[j] = 0.0f;
}

// state: [B=8, 9, 512, 512] f32. slices 0..6 = x_t, 7 = vx, 8 = vy.
// Stage 1: 1024 blocks = 8 batches (bid&7 -> XCD-pinned) x 128 four-row tiles.
// Each wave processes one full 512-px row across all 7 t-slices.
__global__ __launch_bounds__(256) void phi_q_stage1(const float* __restrict__ state,
                                                    float* __restrict__ ws) {
    const int bid  = blockIdx.x;
    const int b    = bid & 7;        // batch == XCD (round-robin dispatch)
    const int yt   = bid >> 3;       // y-tile of 4 rows
    const int tid  = threadIdx.x;
    const int wid  = tid >> 6;       // wave -> row within tile
    const int lane = tid & 63;
    const int y    = yt * 4 + wid;

    const size_t slice  = (size_t)N * N;
    const float* base   = state + (size_t)b * 9 * slice;
    const size_t rowoff = (size_t)y * N + lane * 8;

    // Diffusion tensor for this row's 8 px (loaded once, reused for all 7 t).
    const float4 vxA = *reinterpret_cast<const float4*>(base + 7 * slice + rowoff);
    const float4 vxB = *reinterpret_cast<const float4*>(base + 7 * slice + rowoff + 4);
    const float4 vyA = *reinterpret_cast<const float4*>(base + 8 * slice + rowoff);
    const float4 vyB = *reinterpret_cast<const float4*>(base + 8 * slice + rowoff + 4);
    float H11[8], H12[8], H22[8];
    {
        const float vxs[8] = {vxA.x, vxA.y, vxA.z, vxA.w, vxB.x, vxB.y, vxB.z, vxB.w};
        const float vys[8] = {vyA.x, vyA.y, vyA.z, vyA.w, vyB.x, vyB.y, vyB.z, vyB.w};
        #pragma unroll
        for (int j = 0; j < 8; ++j) {
            H11[j] = GAMMA + BETA * vxs[j] * vxs[j];
            H12[j] = BETA * vxs[j] * vys[j];
            H22[j] = GAMMA + BETA * vys[j] * vys[j];
        }
    }

    const bool ym = (y > 0), yp = (y < N - 1);   // wave-uniform

    float q = 0.0f;
    float prevc[8];
    #pragma unroll
    for (int j = 0; j < 8; ++j) prevc[j] = 0.0f;

    #pragma unroll
    for (int t = 0; t < 7; ++t) {
        const float* u = base + (size_t)t * slice;
        float sm[10], sc[10], su[10];

        loadspan10(u + rowoff, lane, sc);
        if (ym) loadspan10(u + rowoff - N, lane, sm);
        else    zero10(sm);
        if (yp) loadspan10(u + rowoff + N, lane, su);
        else    zero10(su);

        #pragma unroll
        for (int j = 0; j < 8; ++j) {
            const float c   = sc[j + 1];
            const float uxx = sc[j] + sc[j + 2] - 2.0f * c;
            const float uyy = sm[j + 1] + su[j + 1] - 2.0f * c;
            const float uxy = 0.25f * (su[j + 2] - su[j] - sm[j + 2] + sm[j]);
            const float div = H11[j] * uxx + 2.0f * H12[j] * uxy + H22[j] * uyy;
            const float Ax  = KAPPA2 * c - div;
            const float Mx  = c + Ax;   // DT = 1

            if (t == 0) {
                q += Ax * Ax + 1.05f * c * c;
            } else {
                q += Mx * Mx;
                if (t < 6) q += c * c;
                q -= 2.0f * prevc[j] * Mx;
            }
            prevc[j] = c;
        }
    }

    // wave reduce + block reduce -> one partial per block
    #pragma unroll
    for (int off = 32; off > 0; off >>= 1)
        q += __shfl_down(q, off, 64);

    __shared__ float sred[4];
    if (lane == 0) sred[wid] = q;
    __syncthreads();
    if (tid == 0) ws[bid] = sred[0] + sred[1] + sred[2] + sred[3];
}

// Stage 2: 8 blocks; block b sums the 128 partials of batch b (ws[b + 8k]).
__global__ __launch_bounds__(128) void phi_q_stage2(const float* __restrict__ ws,
                                                    float* __restrict__ out) {
    const int b = blockIdx.x;
    float v = ws[b + 8 * threadIdx.x];
    #pragma unroll
    for (int off = 32; off > 0; off >>= 1)
        v += __shfl_down(v, off, 64);

    __shared__ float sred[2];
    const int lane = threadIdx.x & 63;
    const int wid  = threadIdx.x >> 6;
    if (lane == 0) sred[wid] = v;
    __syncthreads();
    if (threadIdx.x == 0) out[b] = sred[0] + sred[1];
}

extern "C" void kernel_launch(void* const* d_in, const int* in_sizes, int n_in,
                              void* d_out, int out_size, void* d_ws, size_t ws_size,
                              hipStream_t stream) {
    const float* state = (const float*)d_in[0];
    float* out = (float*)d_out;
    float* ws  = (float*)d_ws;

    phi_q_stage1<<<1024, 256, 0, stream>>>(state, ws);
    phi_q_stage2<<<8, 128, 0, stream>>>(ws, out);
}